// Round 10
// baseline (39.427 us; speedup 1.0000x reference)
//
#include <hip/hip_runtime.h>
#include <math.h>

struct V2 { float x, y; };

#define NT 128           // threads per block; each thread does 2 pairs
#define PPB (2 * NT)     // pairs per block

// angle class matching atan2 range ordering: 0: y<0 (-pi,0); 1: y==0,x>=0 {0};
// 2: y>0 (0,pi); 3: y==0,x<0 {pi}
__device__ __forceinline__ int ang_class(float x, float y) {
    return (y < 0.f) ? 0 : ((y > 0.f) ? 2 : ((x >= 0.f) ? 1 : 3));
}

// Ascending sort of 4 points by exact atan2 ordering around the centroid,
// as a 5-comparator network. Comparator is exact (f64 cross), deviating from
// jnp.argsort only on exact angle ties (measure zero).
__device__ __forceinline__ void angle_sort4(float4 lo, float4 hi, V2 out[4]) {
    float x[4] = {lo.x, lo.z, hi.x, hi.z};
    float y[4] = {lo.y, lo.w, hi.y, hi.w};
    float cx = (((x[0] + x[1]) + x[2]) + x[3]) * 0.25f;
    float cy = (((y[0] + y[1]) + y[2]) + y[3]) * 0.25f;
    float rx[4], ry[4]; int cl[4];
#pragma unroll
    for (int i = 0; i < 4; i++) {
        rx[i] = x[i] - cx; ry[i] = y[i] - cy;
        cl[i] = ang_class(rx[i], ry[i]);
    }
#define CE(i, j) { \
    int cd = cl[i] - cl[j]; \
    double cr = (double)rx[i] * (double)ry[j] - (double)ry[i] * (double)rx[j]; \
    bool gt = (cd > 0) || (cd == 0 && cr < 0.0);  /* ang_i > ang_j -> swap */ \
    float t; int ti; \
    t = x[i];  x[i]  = gt ? x[j]  : x[i];  x[j]  = gt ? t  : x[j]; \
    t = y[i];  y[i]  = gt ? y[j]  : y[i];  y[j]  = gt ? t  : y[j]; \
    t = rx[i]; rx[i] = gt ? rx[j] : rx[i]; rx[j] = gt ? t  : rx[j]; \
    t = ry[i]; ry[i] = gt ? ry[j] : ry[i]; ry[j] = gt ? t  : ry[j]; \
    ti = cl[i]; cl[i] = gt ? cl[j] : cl[i]; cl[j] = gt ? ti : cl[j]; \
}
    CE(0, 1) CE(2, 3) CE(0, 2) CE(1, 3) CE(1, 2)
#undef CE
#pragma unroll
    for (int k = 0; k < 4; k++) { out[k].x = x[k]; out[k].y = y[k]; }
}

// One Sutherland-Hodgman round for BOTH pairs, interleaved (ILP-2), in-place
// in LDS. Branch-free: invalid emissions land in trash row 8.
__device__ __forceinline__ void clip_mid2(float2 (*buf)[PPB],
                                          const V2* A, const V2* B,
                                          int* nv, int tid)
{
    float ex[2], ey[2], qx[2][8], qy[2][8], d[2][8];
#pragma unroll
    for (int p = 0; p < 2; p++) {
        ex[p] = B[p].x - A[p].x; ey[p] = B[p].y - A[p].y;
#pragma unroll
        for (int s = 0; s < 8; s++) {
            float2 v = buf[s][tid + p * NT];
            qx[p][s] = v.x; qy[p][s] = v.y;
            d[p][s] = ex[p] * (v.y - A[p].y) - ey[p] * (v.x - A[p].x);
        }
    }
    int cnt[2] = {0, 0};
#pragma unroll
    for (int idx = 0; idx < 8; idx++) {
#pragma unroll
        for (int p = 0; p < 2; p++) {
            // next vertex: poly[(idx+1) % max(nv,1)] with JAX index-clamp
            float nxx, nxy, dn;
            if (idx == 7) {
                bool w = (nv[p] == 8);   // nv>8 -> index 8 clamps to slot 7
                nxx = w ? qx[p][0] : qx[p][7];
                nxy = w ? qy[p][0] : qy[p][7];
                dn  = w ? d[p][0]  : d[p][7];
            } else {
                bool w = ((idx + 1) == nv[p]);
                nxx = w ? qx[p][0] : qx[p][idx + 1];
                nxy = w ? qy[p][0] : qy[p][idx + 1];
                dn  = w ? d[p][0]  : d[p][idx + 1];
            }
            bool active = idx < nv[p];
            bool in_cur = d[p][idx] >= 0.f;
            bool in_nxt = dn >= 0.f;
            float den = d[p][idx] - dn;
            den = (fabsf(den) < 1e-12f) ? 1e-12f : den;
            float t = __fdividef(d[p][idx], den);
            float ix = qx[p][idx] + t * (nxx - qx[p][idx]);
            float iy = qy[p][idx] + t * (nxy - qy[p][idx]);
            bool v0 = active && in_cur;
            bool v1 = active && (in_cur != in_nxt);
            int s0 = (v0 && cnt[p] < 8) ? cnt[p] : 8;
            buf[s0][tid + p * NT] = make_float2(qx[p][idx], qy[p][idx]);
            cnt[p] += v0 ? 1 : 0;
            int s1 = (v1 && cnt[p] < 8) ? cnt[p] : 8;
            buf[s1][tid + p * NT] = make_float2(ix, iy);
            cnt[p] += v1 ? 1 : 0;
        }
    }
    nv[0] = cnt[0]; nv[1] = cnt[1];
}

// Final round for BOTH pairs: clip fused with shoelace (no LDS writes).
// Emission order == slot order; wrap term last == reference FP sum order.
__device__ __forceinline__ void clip_final2(const float2 (*buf)[PPB],
                                            const V2* A, const V2* B,
                                            const int* nv, int tid,
                                            float* inter)
{
    float ex[2], ey[2], qx[2][8], qy[2][8], d[2][8];
#pragma unroll
    for (int p = 0; p < 2; p++) {
        ex[p] = B[p].x - A[p].x; ey[p] = B[p].y - A[p].y;
#pragma unroll
        for (int s = 0; s < 8; s++) {
            float2 v = buf[s][tid + p * NT];
            qx[p][s] = v.x; qy[p][s] = v.y;
            d[p][s] = ex[p] * (v.y - A[p].y) - ey[p] * (v.x - A[p].x);
        }
    }
    int cnt[2] = {0, 0};
    float sx[2] = {0.f, 0.f};
    float fx[2] = {0.f, 0.f}, fy[2] = {0.f, 0.f};
    float px[2] = {0.f, 0.f}, py[2] = {0.f, 0.f};
#pragma unroll
    for (int idx = 0; idx < 8; idx++) {
#pragma unroll
        for (int p = 0; p < 2; p++) {
            float nxx, nxy, dn;
            if (idx == 7) {
                bool w = (nv[p] == 8);
                nxx = w ? qx[p][0] : qx[p][7];
                nxy = w ? qy[p][0] : qy[p][7];
                dn  = w ? d[p][0]  : d[p][7];
            } else {
                bool w = ((idx + 1) == nv[p]);
                nxx = w ? qx[p][0] : qx[p][idx + 1];
                nxy = w ? qy[p][0] : qy[p][idx + 1];
                dn  = w ? d[p][0]  : d[p][idx + 1];
            }
            bool active = idx < nv[p];
            bool in_cur = d[p][idx] >= 0.f;
            bool in_nxt = dn >= 0.f;
            float den = d[p][idx] - dn;
            den = (fabsf(den) < 1e-12f) ? 1e-12f : den;
            float t = __fdividef(d[p][idx], den);
            float ix = qx[p][idx] + t * (nxx - qx[p][idx]);
            float iy = qy[p][idx] + t * (nxy - qy[p][idx]);
            bool v0 = active && in_cur;
            bool v1 = active && (in_cur != in_nxt);
            {
                bool w0 = (cnt[p] == 0), wl = (cnt[p] <= 7);
                if (v0) {
                    fx[p] = w0 ? qx[p][idx] : fx[p];
                    fy[p] = w0 ? qy[p][idx] : fy[p];
                    sx[p] += (!w0 && wl) ? (px[p] * qy[p][idx] - qx[p][idx] * py[p]) : 0.f;
                    px[p] = wl ? qx[p][idx] : px[p];
                    py[p] = wl ? qy[p][idx] : py[p];
                }
                cnt[p] += v0 ? 1 : 0;
            }
            {
                bool w0 = (cnt[p] == 0), wl = (cnt[p] <= 7);
                if (v1) {
                    fx[p] = w0 ? ix : fx[p];
                    fy[p] = w0 ? iy : fy[p];
                    sx[p] += (!w0 && wl) ? (px[p] * iy - ix * py[p]) : 0.f;
                    px[p] = wl ? ix : px[p];
                    py[p] = wl ? iy : py[p];
                }
                cnt[p] += v1 ? 1 : 0;
            }
        }
    }
#pragma unroll
    for (int p = 0; p < 2; p++) {
        if (cnt[p] > 0 && cnt[p] <= 8) sx[p] += px[p] * fy[p] - fx[p] * py[p];
        inter[p] = 0.5f * fabsf(sx[p]);
    }
}

__global__ __launch_bounds__(NT, 4) void poly_iou_kernel(
    const float* __restrict__ preds, const float* __restrict__ targets,
    float* __restrict__ out, int n)
{
    __shared__ float2 buf[9][PPB];   // 18 KB: 8 slots + trash row, 2 cols/thread
    int tid = threadIdx.x;
    int gid0 = blockIdx.x * PPB + tid;
    int gid1 = gid0 + NT;
    // clamp load indices (straight-line tail handling); stores are guarded
    int g0 = min(gid0, n - 1);
    int g1 = min(gid1, n - 1);

    const float4* p4 = reinterpret_cast<const float4*>(preds);
    const float4* t4 = reinterpret_cast<const float4*>(targets);

    V2 P[2][4], T[2][4];
    {
        float4 a0 = p4[2 * g0], a1 = p4[2 * g0 + 1];
        float4 b0 = t4[2 * g0], b1 = t4[2 * g0 + 1];
        float4 a2 = p4[2 * g1], a3 = p4[2 * g1 + 1];
        float4 b2 = t4[2 * g1], b3 = t4[2 * g1 + 1];
        angle_sort4(a0, a1, P[0]);
        angle_sort4(b0, b1, T[0]);
        angle_sort4(a2, a3, P[1]);
        angle_sort4(b2, b3, T[1]);
    }

    // ---- edge 0 (nv=4 compile-time): registers -> buf, both pairs ----
    int nv[2];
#pragma unroll
    for (int p = 0; p < 2; p++) {
        float ex = T[p][1].x - T[p][0].x, ey = T[p][1].y - T[p][0].y;
        float dd[4];
#pragma unroll
        for (int k = 0; k < 4; k++)
            dd[k] = ex * (P[p][k].y - T[p][0].y) - ey * (P[p][k].x - T[p][0].x);
        int cnt = 0;
#pragma unroll
        for (int idx = 0; idx < 4; idx++) {
            int j = (idx + 1) & 3;
            bool in_cur = dd[idx] >= 0.f;
            bool in_nxt = dd[j] >= 0.f;
            float den = dd[idx] - dd[j];
            den = (fabsf(den) < 1e-12f) ? 1e-12f : den;
            float t = __fdividef(dd[idx], den);
            float ix = P[p][idx].x + t * (P[p][j].x - P[p][idx].x);
            float iy = P[p][idx].y + t * (P[p][j].y - P[p][idx].y);
            bool v1 = (in_cur != in_nxt);
            int s0 = in_cur ? cnt : 8;              // cnt <= 7 here always
            buf[s0][tid + p * NT] = make_float2(P[p][idx].x, P[p][idx].y);
            cnt += in_cur ? 1 : 0;
            int s1 = v1 ? cnt : 8;
            buf[s1][tid + p * NT] = make_float2(ix, iy);
            cnt += v1 ? 1 : 0;
        }
        nv[p] = cnt;
    }

    // ---- edges 1..2 in place; edge 3 fused with shoelace ----
    V2 A[2], B[2];
    A[0] = T[0][1]; B[0] = T[0][2]; A[1] = T[1][1]; B[1] = T[1][2];
    clip_mid2(buf, A, B, nv, tid);
    A[0] = T[0][2]; B[0] = T[0][3]; A[1] = T[1][2]; B[1] = T[1][3];
    clip_mid2(buf, A, B, nv, tid);
    A[0] = T[0][3]; B[0] = T[0][0]; A[1] = T[1][3]; B[1] = T[1][0];
    float inter[2];
    clip_final2(buf, A, B, nv, tid, inter);

    // ---- convex hull (gift wrap, serial scan, both pairs interleaved) ----
    float hx[2][8], hy[2][8];
#pragma unroll
    for (int p = 0; p < 2; p++) {
#pragma unroll
        for (int k = 0; k < 4; k++) {
            hx[p][k] = P[p][k].x;     hy[p][k] = P[p][k].y;
            hx[p][4 + k] = T[p][k].x; hy[p][4 + k] = T[p][k].y;
        }
    }

    int start[2]; float vsx[2], vsy[2];
#pragma unroll
    for (int p = 0; p < 2; p++) {
        start[p] = 0; vsx[p] = hx[p][0]; vsy[p] = hy[p][0];
#pragma unroll
        for (int k = 1; k < 8; k++) {       // first-index argmin of y
            bool b = hy[p][k] < vsy[p];
            start[p] = b ? k : start[p];
            vsx[p] = b ? hx[p][k] : vsx[p];
            vsy[p] = b ? hy[p][k] : vsy[p];
        }
    }

    float pcx[2], pcy[2], harea[2];
    int cur[2]; bool done[2];
#pragma unroll
    for (int p = 0; p < 2; p++) {
        pcx[p] = vsx[p]; pcy[p] = vsy[p];
        cur[p] = start[p]; done[p] = false; harea[p] = 0.f;
    }
#pragma unroll 1
    for (int s = 0; s < 8; s++) {
#pragma unroll
        for (int p = 0; p < 2; p++) {
            int best = cur[p];
            float bx = 0.f, by = 0.f, bd = 0.f, px = pcx[p], py = pcy[p];
#pragma unroll
            for (int k = 0; k < 8; k++) {
                float rx = hx[p][k] - pcx[p], ry = hy[p][k] - pcy[p];
                float d2 = rx * rx + ry * ry;
                bool ok = d2 > 1e-12f;
                float c = bx * ry - by * rx;    // cross(best, k)
                bool take = ok && ((c < 0.f) || ((c == 0.f) && (d2 > bd)));
                best = take ? k : best;
                bx = take ? rx : bx; by = take ? ry : by; bd = take ? d2 : bd;
                px = take ? hx[p][k] : px; py = take ? hy[p][k] : py;
            }
            int nxt = done[p] ? cur[p] : best;
            float pvx = done[p] ? pcx[p] : px;
            float pvy = done[p] ? pcy[p] : py;
            harea[p] += pcx[p] * pvy - pvx * pcy[p];  // stay-steps add exact 0
            done[p] = done[p] || (nxt == start[p]);
            pcx[p] = pvx; pcy[p] = pvy; cur[p] = nxt;
        }
        if (__all(done[0] && done[1])) break;   // skipped steps add exact 0
    }

#pragma unroll
    for (int p = 0; p < 2; p++) {
        harea[p] += pcx[p] * vsy[p] - vsx[p] * pcy[p];   // closure
        harea[p] = 0.5f * fabsf(harea[p]);
    }

    float iou0 = (harea[0] > 1e-12f) ? (inter[0] / fmaxf(harea[0], 1e-12f)) : 0.f;
    float iou1 = (harea[1] > 1e-12f) ? (inter[1] / fmaxf(harea[1], 1e-12f)) : 0.f;
    if (gid0 < n) out[gid0] = 1.f - iou0;
    if (gid1 < n) out[gid1] = 1.f - iou1;
}

extern "C" void kernel_launch(void* const* d_in, const int* in_sizes, int n_in,
                              void* d_out, int out_size, void* d_ws, size_t ws_size,
                              hipStream_t stream) {
    const float* preds = (const float*)d_in[0];
    const float* targets = (const float*)d_in[1];
    float* out = (float*)d_out;
    int n = in_sizes[0] / 8;
    int grid = (n + PPB - 1) / PPB;
    hipLaunchKernelGGL(poly_iou_kernel, dim3(grid), dim3(NT), 0, stream,
                       preds, targets, out, n);
}

// Round 11
// 32.544 us; speedup vs baseline: 1.2115x; 1.2115x over previous
//
#include <hip/hip_runtime.h>
#include <math.h>

struct V2 { float x, y; };

#define NT 256

// angle class matching atan2 range ordering: 0: y<0 (-pi,0); 1: y==0,x>=0 {0};
// 2: y>0 (0,pi); 3: y==0,x<0 {pi}
__device__ __forceinline__ int ang_class(float x, float y) {
    return (y < 0.f) ? 0 : ((y > 0.f) ? 2 : ((x >= 0.f) ? 1 : 3));
}

// Stable ascending argsort of 4 points by exact atan2 ordering around centroid.
// 6 pairwise comparisons; double products of float32 are exact.
__device__ __forceinline__ void angle_sort4(float4 lo, float4 hi, V2 out[4]) {
    V2 p[4];
    p[0].x = lo.x; p[0].y = lo.y;
    p[1].x = lo.z; p[1].y = lo.w;
    p[2].x = hi.x; p[2].y = hi.y;
    p[3].x = hi.z; p[3].y = hi.w;
    float cx = (((p[0].x + p[1].x) + p[2].x) + p[3].x) * 0.25f;
    float cy = (((p[0].y + p[1].y) + p[2].y) + p[3].y) * 0.25f;
    float rx[4], ry[4]; int cls[4];
#pragma unroll
    for (int i = 0; i < 4; i++) {
        rx[i] = p[i].x - cx; ry[i] = p[i].y - cy;
        cls[i] = ang_class(rx[i], ry[i]);
    }
    int rank[4] = {0, 0, 0, 0};
#pragma unroll
    for (int i = 0; i < 4; i++) {
#pragma unroll
        for (int j = i + 1; j < 4; j++) {
            int cd = cls[i] - cls[j];
            // cr > 0 -> ang_i < ang_j ; cr == 0 for the y==0 classes (exact)
            double cr = (double)rx[i] * (double)ry[j] - (double)ry[i] * (double)rx[j];
            bool gt = (cd > 0) || (cd == 0 && cr < 0.0);  // ang_i > ang_j
            rank[i] += gt ? 1 : 0;
            rank[j] += gt ? 0 : 1;   // includes equal-angle stable tie (i<j)
        }
    }
#pragma unroll
    for (int k = 0; k < 4; k++) {
#pragma unroll
        for (int i = 0; i < 4; i++) {
            if (rank[i] == k) out[k] = p[i];
        }
    }
}

// One Sutherland-Hodgman round, IN-PLACE: reads all 8 slots of this thread's
// column into registers, clips by edge A->B, compacts back into same column.
__device__ __forceinline__ int clip_round(float2 (*buf)[NT], V2 A, V2 B,
                                          int nv, int tid)
{
    float ex = B.x - A.x, ey = B.y - A.y;
    V2 p[8]; float d[8];
#pragma unroll
    for (int s = 0; s < 8; s++) {
        float2 v = buf[s][tid];
        p[s].x = v.x; p[s].y = v.y;
        d[s] = ex * (v.y - A.y) - ey * (v.x - A.x);
    }
    int cnt = 0;
#pragma unroll
    for (int idx = 0; idx < 8; idx++) {
        // next vertex: replicates poly[(idx+1) % max(nv,1)] with JAX index-clamp
        V2 nx; float dn;
        if (idx == 7) {
            bool w = (nv == 8);          // nv>8 -> index 8 clamps to slot 7 (self)
            nx.x = w ? p[0].x : p[7].x;
            nx.y = w ? p[0].y : p[7].y;
            dn   = w ? d[0]   : d[7];
        } else {
            bool w = ((idx + 1) == nv);
            nx.x = w ? p[0].x : p[idx + 1].x;
            nx.y = w ? p[0].y : p[idx + 1].y;
            dn   = w ? d[0]   : d[idx + 1];
        }
        bool active = idx < nv;
        bool in_cur = d[idx] >= 0.f;
        bool in_nxt = dn >= 0.f;
        float den = d[idx] - dn;
        den = (fabsf(den) < 1e-12f) ? 1e-12f : den;
        float t = __fdividef(d[idx], den);
        float ix = p[idx].x + t * (nx.x - p[idx].x);
        float iy = p[idx].y + t * (nx.y - p[idx].y);
        bool v0 = active && in_cur;
        bool v1 = active && (in_cur != in_nxt);
        if (v0 && cnt < 8) buf[cnt][tid] = make_float2(p[idx].x, p[idx].y);
        cnt += v0 ? 1 : 0;
        if (v1 && cnt < 8) buf[cnt][tid] = make_float2(ix, iy);
        cnt += v1 ? 1 : 0;
    }
    return cnt;   // unclamped count, like the reference
}

__global__ __launch_bounds__(256, 8) void poly_iou_kernel(
    const float* __restrict__ preds, const float* __restrict__ targets,
    float* __restrict__ out, int n)
{
    __shared__ float2 buf[8][NT];   // 16 KB: per-thread 8-slot scratch column
    int tid = threadIdx.x;
    int gid = blockIdx.x * NT + tid;
    if (gid >= n) return;

    const float4* p4 = reinterpret_cast<const float4*>(preds);
    const float4* t4 = reinterpret_cast<const float4*>(targets);
    float4 a0 = p4[2 * gid], a1 = p4[2 * gid + 1];
    float4 b0 = t4[2 * gid], b1 = t4[2 * gid + 1];

    V2 P[4], T[4];
    angle_sort4(a0, a1, P);
    angle_sort4(b0, b1, T);

    // ---- edge 0 (nv=4 compile-time): registers -> buf ----
    int nv;
    {
        float ex = T[1].x - T[0].x, ey = T[1].y - T[0].y;
        float dd[4];
#pragma unroll
        for (int k = 0; k < 4; k++)
            dd[k] = ex * (P[k].y - T[0].y) - ey * (P[k].x - T[0].x);
        int cnt = 0;
#pragma unroll
        for (int idx = 0; idx < 4; idx++) {
            int j = (idx + 1) & 3;
            bool in_cur = dd[idx] >= 0.f;
            bool in_nxt = dd[j] >= 0.f;
            float den = dd[idx] - dd[j];
            den = (fabsf(den) < 1e-12f) ? 1e-12f : den;
            float t = __fdividef(dd[idx], den);
            float ix = P[idx].x + t * (P[j].x - P[idx].x);
            float iy = P[idx].y + t * (P[j].y - P[idx].y);
            bool v1 = (in_cur != in_nxt);
            if (in_cur) buf[cnt][tid] = make_float2(P[idx].x, P[idx].y);
            cnt += in_cur ? 1 : 0;
            if (v1) buf[cnt][tid] = make_float2(ix, iy);
            cnt += v1 ? 1 : 0;
        }
        nv = cnt;   // max 8 from 4 vertices, no drop possible
    }

    // ---- edges 1..3, in place ----
    nv = clip_round(buf, T[1], T[2], nv, tid);
    nv = clip_round(buf, T[2], T[3], nv, tid);
    nv = clip_round(buf, T[3], T[0], nv, tid);

    // ---- shoelace of final polygon ----
    float inter = 0.f;
    {
        V2 q[8];
#pragma unroll
        for (int s = 0; s < 8; s++) {
            float2 v = buf[s][tid];
            q[s].x = v.x; q[s].y = v.y;
        }
#pragma unroll
        for (int idx = 0; idx < 8; idx++) {
            V2 nx;
            if (idx == 7) {
                bool w = (nv == 8);
                nx.x = w ? q[0].x : q[7].x;
                nx.y = w ? q[0].y : q[7].y;
            } else {
                bool w = ((idx + 1) == nv);
                nx.x = w ? q[0].x : q[idx + 1].x;
                nx.y = w ? q[0].y : q[idx + 1].y;
            }
            bool active = idx < nv;
            float term = q[idx].x * nx.y - nx.x * q[idx].y;
            inter += active ? term : 0.f;
        }
        inter = 0.5f * fabsf(inter);
    }

    // ---- convex hull (gift wrap, O(n) per step) of the 8 sorted points ----
    V2 h[8];
#pragma unroll
    for (int k = 0; k < 4; k++) { h[k] = P[k]; h[4 + k] = T[k]; }

    int start = 0; V2 vs = h[0];
#pragma unroll
    for (int k = 1; k < 8; k++) {           // first-index argmin of y
        bool b = h[k].y < vs.y;
        start = b ? k : start;
        vs.x  = b ? h[k].x : vs.x;
        vs.y  = b ? h[k].y : vs.y;
    }

    V2 pc = vs; int cur = start; bool done = false; float harea = 0.f;
#pragma unroll 1
    for (int s = 0; s < 8; s++) {
        // most-clockwise ray from pc; farthest on collinear; first index on tie.
        // bx=by=0 start: first valid k takes via (c==0 && d2>bd), bd=0.
        int best = cur;
        float bx = 0.f, by = 0.f, bd = 0.f, px = pc.x, py = pc.y;
#pragma unroll
        for (int k = 0; k < 8; k++) {
            float rx = h[k].x - pc.x, ry = h[k].y - pc.y;
            float d2 = rx * rx + ry * ry;
            bool ok = d2 > 1e-12f;
            float c = bx * ry - by * rx;    // cross(best, k)
            bool take = ok && ((c < 0.f) || ((c == 0.f) && (d2 > bd)));
            best = take ? k : best;
            bx = take ? rx : bx; by = take ? ry : by; bd = take ? d2 : bd;
            px = take ? h[k].x : px; py = take ? h[k].y : py;
        }
        int nxt = done ? cur : best;
        V2 pv;
        pv.x = done ? pc.x : px;
        pv.y = done ? pc.y : py;
        harea += pc.x * pv.y - pv.x * pc.y;  // stay-steps add exact 0
        done = done || (nxt == start);
        pc = pv; cur = nxt;
        if (__all(done)) break;              // skipped steps contribute exact 0
    }
    harea += pc.x * vs.y - vs.x * pc.y;     // closure
    harea = 0.5f * fabsf(harea);

    float iou = (harea > 1e-12f) ? (inter / fmaxf(harea, 1e-12f)) : 0.f;
    out[gid] = 1.f - iou;
}

extern "C" void kernel_launch(void* const* d_in, const int* in_sizes, int n_in,
                              void* d_out, int out_size, void* d_ws, size_t ws_size,
                              hipStream_t stream) {
    const float* preds = (const float*)d_in[0];
    const float* targets = (const float*)d_in[1];
    float* out = (float*)d_out;
    int n = in_sizes[0] / 8;
    int block = NT;
    int grid = (n + block - 1) / block;
    hipLaunchKernelGGL(poly_iou_kernel, dim3(grid), dim3(block), 0, stream,
                       preds, targets, out, n);
}